// Round 4
// baseline (493.925 us; speedup 1.0000x reference)
//
#include <hip/hip_runtime.h>

// FeatureAggregationModule on MI355X.  OUTPUT IS FLOAT32 (reference is pure
// f32 JAX math; round 0-3 failures were bf16 writes into the f32 d_out).
//
// Decomposition:
//   feat = ReLU(A*x + bias)            A = conv_w * bn_scale*rsqrt(var+eps)  (bf16 MFMA GEMM)
//   Q = qw*feat, K = kw*feat           (bf16 MFMA, fused L2-norm -> QnT, Kn)
//   KF = Kn * feat^T, fsum = sum_n feat
//   matrix[m,c]   = sum_c' vw[c,c']*KF[m,c'] + vb[c]*Ksum[m]   (V eliminated)
//   value_sum[c]  = vw[c,:]*fsum + N*vb[c]
//   tailor[n]     = 1/(N + sum_m Qn[m,n]*(Ksum[m]+eps))
//   out = feat*(feat + gamma*tailor*(value_sum + matrix^T*Qn) + 1)
//
// feat storage: bf16 in ws if ws_size permits (~96 MB), else f32 in d_out
// (k_out then does same-index in-place RMW -> no cross-thread hazard).

typedef short short8 __attribute__((ext_vector_type(8)));
typedef __bf16 bf16x8 __attribute__((ext_vector_type(8)));
typedef float f32x4 __attribute__((ext_vector_type(4)));

#define DEVFN static __device__ __forceinline__

static constexpr int NB = 16;       // batch
static constexpr int C = 256;       // channels (Cout = Cin)
static constexpr int HW = 9216;     // 96*96
static constexpr float FN = 9216.0f;
static constexpr float EPS_ATT_C = 1e-6f;
static constexpr float EPS_BN_C = 1e-5f;

DEVFN unsigned short f2b(float f) {
  unsigned u = __float_as_uint(f);
  u += 0x7FFFu + ((u >> 16) & 1u);   // RNE (no NaN inputs here)
  return (unsigned short)(u >> 16);
}
DEVFN float b2f(unsigned short s) { return __uint_as_float(((unsigned)s) << 16); }

// feat-storage helpers (FT = unsigned short (bf16 bits) or float)
DEVFN float featval(float v) { return v; }
DEVFN float featval(unsigned short v) { return b2f(v); }
DEVFN short featbits(float v) { return (short)f2b(v); }
DEVFN short featbits(unsigned short v) { return (short)v; }
DEVFN void feat_store(float* p, float v) { *p = v; }
DEVFN void feat_store(unsigned short* p, float v) { *p = f2b(v); }

DEVFN f32x4 mfma16(short8 a, short8 b, f32x4 c) {
  return __builtin_amdgcn_mfma_f32_16x16x32_bf16(
      __builtin_bit_cast(bf16x8, a), __builtin_bit_cast(bf16x8, b), c, 0, 0, 0);
}

// ---------------------------------------------------------------- k_prep
__global__ __launch_bounds__(256) void k_prep(
    const float* __restrict__ conv_w, const float* __restrict__ bn_scale,
    const float* __restrict__ bn_bias, const float* __restrict__ bn_mean,
    const float* __restrict__ bn_var, const float* __restrict__ q_w,
    const float* __restrict__ k_w, const float* __restrict__ v_w,
    unsigned short* __restrict__ Abf, float* __restrict__ biasA,
    unsigned short* __restrict__ qwbf, unsigned short* __restrict__ kwbf,
    float* __restrict__ vwT, float* __restrict__ fsum, float* __restrict__ Ksum,
    float* __restrict__ KF) {
  int tid = blockIdx.x * 256 + threadIdx.x;
  int nth = gridDim.x * 256;
  for (int i = tid; i < 65536; i += nth) {
    int o = i >> 8;
    float sc = bn_scale[o] * rsqrtf(bn_var[o] + EPS_BN_C);
    Abf[i] = f2b(conv_w[i] * sc);
  }
  for (int i = tid; i < 256; i += nth) {
    float sc = bn_scale[i] * rsqrtf(bn_var[i] + EPS_BN_C);
    biasA[i] = bn_bias[i] - bn_mean[i] * sc;
  }
  for (int i = tid; i < 8192; i += nth) {
    qwbf[i] = f2b(q_w[i]);
    kwbf[i] = f2b(k_w[i]);
  }
  for (int i = tid; i < 65536; i += nth) {
    int c = i >> 8, cp = i & 255;
    vwT[cp * 256 + c] = v_w[i];
  }
  for (int i = tid; i < NB * 256; i += nth) fsum[i] = 0.f;
  for (int i = tid; i < NB * 32; i += nth) Ksum[i] = 0.f;
  for (int i = tid; i < NB * 32 * 256; i += nth) KF[i] = 0.f;
}

// ---------------------------------------------------------------- k_conv
// feat[b][o][p] = ReLU(sum_c A[o][c]*x[c][p] + bias[o]); fsum[b][o] += sum_p feat
template <typename FT>
__global__ __launch_bounds__(256) void k_conv(
    const float* __restrict__ fsp, const float* __restrict__ fcp,
    const unsigned short* __restrict__ Abf, const float* __restrict__ biasA,
    FT* __restrict__ feat, float* __restrict__ fsum) {
  const int b = blockIdx.y;
  const int p0 = blockIdx.x * 64;
  const int tid = threadIdx.x;
  const int w = tid >> 6, lane = tid & 63, g = lane >> 4, li = lane & 15;

  f32x4 acc[4][4];
#pragma unroll
  for (int i = 0; i < 4; ++i)
#pragma unroll
    for (int j = 0; j < 4; ++j) acc[i][j] = f32x4{0.f, 0.f, 0.f, 0.f};

  const short* Ab = (const short*)Abf;

#pragma unroll 1
  for (int kk = 0; kk < 256; kk += 32) {
    short8 af[4];
#pragma unroll
    for (int i = 0; i < 4; ++i) {
      int o = w * 64 + i * 16 + li;
      af[i] = *(const short8*)(Ab + o * 256 + kk + g * 8);
    }
    const float* src = (kk < 128) ? (fsp + ((size_t)b * 128 + kk) * HW)
                                  : (fcp + ((size_t)b * 128 + (kk - 128)) * HW);
    short8 bfr[4];
#pragma unroll
    for (int j = 0; j < 4; ++j) {
      const float* sp = src + (size_t)g * 8 * HW + p0 + j * 16 + li;
#pragma unroll
      for (int jj = 0; jj < 8; ++jj) bfr[j][jj] = (short)f2b(sp[(size_t)jj * HW]);
    }
#pragma unroll
    for (int i = 0; i < 4; ++i)
#pragma unroll
      for (int j = 0; j < 4; ++j)
        acc[i][j] = mfma16(af[i], bfr[j], acc[i][j]);
  }

  FT* fb = feat + (size_t)b * C * HW;
#pragma unroll
  for (int i = 0; i < 4; ++i) {
#pragma unroll
    for (int r = 0; r < 4; ++r) {
      int o = w * 64 + i * 16 + g * 4 + r;
      float bias = biasA[o];
      float s = 0.f;
#pragma unroll
      for (int j = 0; j < 4; ++j) {
        int p = p0 + j * 16 + li;
        float v = fmaxf(acc[i][j][r] + bias, 0.f);
        feat_store(&fb[(size_t)o * HW + p], v);
        s += v;
      }
      s += __shfl_xor(s, 1); s += __shfl_xor(s, 2);
      s += __shfl_xor(s, 4); s += __shfl_xor(s, 8);
      if (li == 0) atomicAdd(&fsum[b * 256 + o], s);
    }
  }
}

// ---------------------------------------------------------------- k_qk
// Q (D=[p][m]) and K (D=[m][p]) from one feat-fragment load; L2-norm over m.
template <typename FT>
__global__ __launch_bounds__(256) void k_qk(
    const FT* __restrict__ feat, const unsigned short* __restrict__ qwbf,
    const unsigned short* __restrict__ kwbf, const float* __restrict__ q_b,
    const float* __restrict__ k_b, unsigned short* __restrict__ QnT,
    unsigned short* __restrict__ Kn, float* __restrict__ Ksum) {
  const int b = blockIdx.y;
  const int tid = threadIdx.x;
  const int w = tid >> 6, lane = tid & 63, g = lane >> 4, li = lane & 15;
  const int p0 = blockIdx.x * 256 + w * 64;

  const FT* fs = feat + (size_t)b * C * HW;
  const short* qw = (const short*)qwbf;
  const short* kw = (const short*)kwbf;

  f32x4 aq[4][2], ak[2][4];
#pragma unroll
  for (int t = 0; t < 4; ++t)
#pragma unroll
    for (int m = 0; m < 2; ++m) {
      aq[t][m] = f32x4{0.f, 0.f, 0.f, 0.f};
      ak[m][t] = f32x4{0.f, 0.f, 0.f, 0.f};
    }

#pragma unroll 1
  for (int kk = 0; kk < 256; kk += 32) {
    short8 ft[4];
#pragma unroll
    for (int t = 0; t < 4; ++t) {
      const FT* f8 = fs + (size_t)(kk + g * 8) * HW + p0 + t * 16 + li;
#pragma unroll
      for (int jj = 0; jj < 8; ++jj) ft[t][jj] = featbits(f8[(size_t)jj * HW]);
    }
    short8 qf[2], kf[2];
#pragma unroll
    for (int m = 0; m < 2; ++m) {
      qf[m] = *(const short8*)(qw + (m * 16 + li) * 256 + kk + g * 8);
      kf[m] = *(const short8*)(kw + (m * 16 + li) * 256 + kk + g * 8);
    }
#pragma unroll
    for (int t = 0; t < 4; ++t)
#pragma unroll
      for (int m = 0; m < 2; ++m)
        aq[t][m] = mfma16(ft[t], qf[m], aq[t][m]);
#pragma unroll
    for (int m = 0; m < 2; ++m)
#pragma unroll
      for (int t = 0; t < 4; ++t)
        ak[m][t] = mfma16(kf[m], ft[t], ak[m][t]);
  }

  // ---- Q epilogue: D row = p = p0+16t+4g+r, col m = 16*jm+li
  float qb0 = q_b[li], qb1 = q_b[16 + li];
#pragma unroll
  for (int t = 0; t < 4; ++t) {
#pragma unroll
    for (int r = 0; r < 4; ++r) {
      float v0 = aq[t][0][r] + qb0;
      float v1 = aq[t][1][r] + qb1;
      float ss = v0 * v0 + v1 * v1;
      ss += __shfl_xor(ss, 1); ss += __shfl_xor(ss, 2);
      ss += __shfl_xor(ss, 4); ss += __shfl_xor(ss, 8);
      float sc = 1.0f / sqrtf(ss);
      int p = p0 + t * 16 + g * 4 + r;
      unsigned short* qp = QnT + ((size_t)b * HW + p) * 32;
      qp[li] = f2b(v0 * sc);
      qp[16 + li] = f2b(v1 * sc);
    }
  }

  // ---- K epilogue: D row = m = 16*mi+4g+r, col p = p0+16t+li
  float kb[2][4];
#pragma unroll
  for (int mi = 0; mi < 2; ++mi)
#pragma unroll
    for (int r = 0; r < 4; ++r) kb[mi][r] = k_b[mi * 16 + g * 4 + r];

  float ks[2][4];
#pragma unroll
  for (int mi = 0; mi < 2; ++mi)
#pragma unroll
    for (int r = 0; r < 4; ++r) ks[mi][r] = 0.f;

#pragma unroll
  for (int t = 0; t < 4; ++t) {
    float v[2][4];
    float ss = 0.f;
#pragma unroll
    for (int mi = 0; mi < 2; ++mi)
#pragma unroll
      for (int r = 0; r < 4; ++r) {
        v[mi][r] = ak[mi][t][r] + kb[mi][r];
        ss += v[mi][r] * v[mi][r];
      }
    ss += __shfl_xor(ss, 16); ss += __shfl_xor(ss, 32);
    float sc = 1.0f / sqrtf(ss);
    int p = p0 + t * 16 + li;
#pragma unroll
    for (int mi = 0; mi < 2; ++mi)
#pragma unroll
      for (int r = 0; r < 4; ++r) {
        float kn = v[mi][r] * sc;
        Kn[((size_t)b * 32 + mi * 16 + g * 4 + r) * HW + p] = f2b(kn);
        ks[mi][r] += kn;
      }
  }
#pragma unroll
  for (int mi = 0; mi < 2; ++mi)
#pragma unroll
    for (int r = 0; r < 4; ++r) {
      float s = ks[mi][r];
      s += __shfl_xor(s, 1); s += __shfl_xor(s, 2);
      s += __shfl_xor(s, 4); s += __shfl_xor(s, 8);
      if (li == 0) atomicAdd(&Ksum[b * 32 + mi * 16 + g * 4 + r], s);
    }
}

// ---------------------------------------------------------------- k_kf
// KF[b][m][c] += sum_{n in tile} Kn[m][n]*feat[c][n]
template <typename FT>
__global__ __launch_bounds__(256) void k_kf(
    const unsigned short* __restrict__ Kn, const FT* __restrict__ feat,
    float* __restrict__ KF) {
  const int b = blockIdx.y;
  const int n0 = blockIdx.x * 256;
  const int tid = threadIdx.x;
  const int w = tid >> 6, lane = tid & 63, g = lane >> 4, li = lane & 15;
  const short* kn = (const short*)Kn + (size_t)b * 32 * HW;
  const FT* fs = feat + (size_t)b * C * HW;

  f32x4 acc[2][4];
#pragma unroll
  for (int mi = 0; mi < 2; ++mi)
#pragma unroll
    for (int j = 0; j < 4; ++j) acc[mi][j] = f32x4{0.f, 0.f, 0.f, 0.f};

#pragma unroll 1
  for (int s = 0; s < 8; ++s) {
    int nn = n0 + s * 32;
    short8 a[2], bb[4];
#pragma unroll
    for (int mi = 0; mi < 2; ++mi)
      a[mi] = *(const short8*)(kn + (size_t)(mi * 16 + li) * HW + nn + g * 8);
#pragma unroll
    for (int j = 0; j < 4; ++j) {
      const FT* fp = fs + (size_t)(w * 64 + j * 16 + li) * HW + nn + g * 8;
      if constexpr (__is_same(FT, unsigned short)) {
        bb[j] = *(const short8*)fp;
      } else {
        f32x4 x0 = *(const f32x4*)fp;
        f32x4 x1 = *(const f32x4*)(fp + 4);
#pragma unroll
        for (int jj = 0; jj < 4; ++jj) {
          bb[j][jj] = (short)f2b(x0[jj]);
          bb[j][4 + jj] = (short)f2b(x1[jj]);
        }
      }
    }
#pragma unroll
    for (int mi = 0; mi < 2; ++mi)
#pragma unroll
      for (int j = 0; j < 4; ++j)
        acc[mi][j] = mfma16(a[mi], bb[j], acc[mi][j]);
  }
  float* kfp = KF + (size_t)b * 32 * 256;
#pragma unroll
  for (int mi = 0; mi < 2; ++mi)
#pragma unroll
    for (int j = 0; j < 4; ++j)
#pragma unroll
      for (int r = 0; r < 4; ++r) {
        int m = mi * 16 + g * 4 + r;
        int c = w * 64 + j * 16 + li;
        atomicAdd(&kfp[m * 256 + c], acc[mi][j][r]);
      }
}

// ---------------------------------------------------------------- k_mat
__global__ __launch_bounds__(256) void k_mat(
    const float* __restrict__ KF, const float* __restrict__ vwT,
    const float* __restrict__ v_b, const float* __restrict__ fsum,
    const float* __restrict__ Ksum, unsigned short* __restrict__ matT,
    float* __restrict__ vsum, float* __restrict__ tsc) {
  __shared__ float kf_l[32 * 256];
  __shared__ float fs_l[256];
  __shared__ float ks_l[32];
  const int b = blockIdx.x;
  const int tid = threadIdx.x;
  for (int i = tid; i < 8192; i += 256) kf_l[i] = KF[b * 8192 + i];
  fs_l[tid] = fsum[b * 256 + tid];
  if (tid < 32) {
    float k0 = Ksum[b * 32 + tid];
    ks_l[tid] = k0;
    tsc[b * 32 + tid] = k0 + EPS_ATT_C;
  }
  __syncthreads();
  const int c = tid;
  float vs = 0.f;
  float mat[32];
#pragma unroll
  for (int m = 0; m < 32; ++m) mat[m] = 0.f;
  for (int cp = 0; cp < 256; ++cp) {
    float wv = vwT[cp * 256 + c];
    vs += wv * fs_l[cp];
#pragma unroll
    for (int m = 0; m < 32; ++m) mat[m] += wv * kf_l[m * 256 + cp];
  }
  float vb = v_b[c];
  vsum[b * 256 + c] = vs + FN * vb;
  unsigned short* mp = matT + ((size_t)b * 256 + c) * 32;
#pragma unroll
  for (int m = 0; m < 32; ++m) mp[m] = f2b(mat[m] + vb * ks_l[m]);
}

// ---------------------------------------------------------------- k_out
// out[c,n] = f*(f + gamma*tailor[n]*(vsum[c] + sum_m matrix[m,c]*Qn[m,n]) + 1)
// out is f32; when FT==float, feat may alias out (same-index RMW: safe).
template <typename FT>
__global__ __launch_bounds__(256) void k_out(
    const FT* feat, const unsigned short* __restrict__ QnT,
    const unsigned short* __restrict__ matT, const float* __restrict__ vsum,
    const float* __restrict__ tsc, const float* __restrict__ gamma,
    float* out) {
  __shared__ float tail_l[64];
  __shared__ float vs_l[256];
  const int b = blockIdx.y;
  const int n0 = blockIdx.x * 64;
  const int tid = threadIdx.x;
  const int w = tid >> 6, lane = tid & 63, g = lane >> 4, li = lane & 15;
  const short* qn = (const short*)QnT + (size_t)b * HW * 32;

  vs_l[tid] = vsum[b * 256 + tid];
  if (tid < 64) {
    const short* qr = qn + (size_t)(n0 + tid) * 32;
    float d = 0.f;
#pragma unroll
    for (int m = 0; m < 32; ++m) d += b2f((unsigned short)qr[m]) * tsc[b * 32 + m];
    tail_l[tid] = 1.0f / (FN + d);
  }
  __syncthreads();

  const short* mt = (const short*)matT + (size_t)b * 256 * 32;
  short8 am[4], bq[4];
#pragma unroll
  for (int i = 0; i < 4; ++i)
    am[i] = *(const short8*)(mt + (w * 64 + i * 16 + li) * 32 + g * 8);
#pragma unroll
  for (int j = 0; j < 4; ++j)
    bq[j] = *(const short8*)(qn + (size_t)(n0 + j * 16 + li) * 32 + g * 8);

  f32x4 acc[4][4];
#pragma unroll
  for (int i = 0; i < 4; ++i)
#pragma unroll
    for (int j = 0; j < 4; ++j) {
      f32x4 z = f32x4{0.f, 0.f, 0.f, 0.f};
      acc[i][j] = mfma16(am[i], bq[j], z);
    }

  const float gam = gamma[0];
  const FT* fb = feat + (size_t)b * C * HW;
  float* ob = out + (size_t)b * C * HW;
#pragma unroll
  for (int i = 0; i < 4; ++i) {
#pragma unroll
    for (int r = 0; r < 4; ++r) {
      int c = w * 64 + i * 16 + g * 4 + r;
      float vsc = vs_l[c];
#pragma unroll
      for (int j = 0; j < 4; ++j) {
        int nl = j * 16 + li;
        float ms = acc[i][j][r] + vsc;
        float wv = tail_l[nl] * ms;
        float f = featval(fb[(size_t)c * HW + n0 + nl]);
        ob[(size_t)c * HW + n0 + nl] = f * (f + gam * wv + 1.0f);
      }
    }
  }
}

// ---------------------------------------------------------------- launch
extern "C" void kernel_launch(void* const* d_in, const int* in_sizes, int n_in,
                              void* d_out, int out_size, void* d_ws, size_t ws_size,
                              hipStream_t stream) {
  const float* fsp = (const float*)d_in[0];
  const float* fcp = (const float*)d_in[1];
  const float* conv_w = (const float*)d_in[2];
  const float* bn_scale = (const float*)d_in[3];
  const float* bn_bias = (const float*)d_in[4];
  const float* bn_mean = (const float*)d_in[5];
  const float* bn_var = (const float*)d_in[6];
  const float* gamma = (const float*)d_in[7];
  const float* q_w = (const float*)d_in[8];
  const float* q_b = (const float*)d_in[9];
  const float* k_w = (const float*)d_in[10];
  const float* k_b = (const float*)d_in[11];
  const float* v_w = (const float*)d_in[12];
  const float* v_b = (const float*)d_in[13];

  char* ws = (char*)d_ws;
  size_t off = 0;
  auto alloc = [&](size_t bytes) {
    off = (off + 255) & ~(size_t)255;
    void* p = ws + off;
    off += bytes;
    return p;
  };
  const size_t featBytesBf16 = (size_t)NB * C * HW * 2;  // 75.5 MB
  // Try bf16-feat-in-ws layout first.
  unsigned short* featB = (unsigned short*)alloc(featBytesBf16);
  unsigned short* QnT  = (unsigned short*)alloc((size_t)NB * HW * 32 * 2); // 9.4 MB
  unsigned short* Kn   = (unsigned short*)alloc((size_t)NB * 32 * HW * 2); // 9.4 MB
  unsigned short* Abf  = (unsigned short*)alloc(65536 * 2);
  float* biasA = (float*)alloc(256 * 4);
  unsigned short* qwbf = (unsigned short*)alloc(8192 * 2);
  unsigned short* kwbf = (unsigned short*)alloc(8192 * 2);
  float* vwT  = (float*)alloc(65536 * 4);
  float* fsum = (float*)alloc(NB * 256 * 4);
  float* Ksum = (float*)alloc(NB * 32 * 4);
  float* tsc  = (float*)alloc(NB * 32 * 4);
  float* KF   = (float*)alloc((size_t)NB * 32 * 256 * 4);
  unsigned short* matT = (unsigned short*)alloc((size_t)NB * 256 * 32 * 2);
  float* vsum = (float*)alloc(NB * 256 * 4);
  const bool bf16path = (off <= ws_size);
  if (!bf16path) {
    // Re-layout without feat in ws; feat lives in d_out as f32.
    off = 0;
    QnT  = (unsigned short*)alloc((size_t)NB * HW * 32 * 2);
    Kn   = (unsigned short*)alloc((size_t)NB * 32 * HW * 2);
    Abf  = (unsigned short*)alloc(65536 * 2);
    biasA = (float*)alloc(256 * 4);
    qwbf = (unsigned short*)alloc(8192 * 2);
    kwbf = (unsigned short*)alloc(8192 * 2);
    vwT  = (float*)alloc(65536 * 4);
    fsum = (float*)alloc(NB * 256 * 4);
    Ksum = (float*)alloc(NB * 32 * 4);
    tsc  = (float*)alloc(NB * 32 * 4);
    KF   = (float*)alloc((size_t)NB * 32 * 256 * 4);
    matT = (unsigned short*)alloc((size_t)NB * 256 * 32 * 2);
    vsum = (float*)alloc(NB * 256 * 4);
  }
  float* featF = (float*)d_out;
  float* out = (float*)d_out;

  k_prep<<<dim3(64), dim3(256), 0, stream>>>(conv_w, bn_scale, bn_bias, bn_mean,
                                             bn_var, q_w, k_w, v_w, Abf, biasA,
                                             qwbf, kwbf, vwT, fsum, Ksum, KF);
  if (bf16path) {
    k_conv<unsigned short><<<dim3(144, 16), dim3(256), 0, stream>>>(fsp, fcp, Abf, biasA, featB, fsum);
    k_qk<unsigned short><<<dim3(36, 16), dim3(256), 0, stream>>>(featB, qwbf, kwbf, q_b, k_b, QnT, Kn, Ksum);
    k_kf<unsigned short><<<dim3(36, 16), dim3(256), 0, stream>>>(Kn, featB, KF);
    k_mat<<<dim3(16), dim3(256), 0, stream>>>(KF, vwT, v_b, fsum, Ksum, matT, vsum, tsc);
    k_out<unsigned short><<<dim3(144, 16), dim3(256), 0, stream>>>(featB, QnT, matT, vsum, tsc, gamma, out);
  } else {
    k_conv<float><<<dim3(144, 16), dim3(256), 0, stream>>>(fsp, fcp, Abf, biasA, featF, fsum);
    k_qk<float><<<dim3(36, 16), dim3(256), 0, stream>>>(featF, qwbf, kwbf, q_b, k_b, QnT, Kn, Ksum);
    k_kf<float><<<dim3(36, 16), dim3(256), 0, stream>>>(Kn, featF, KF);
    k_mat<<<dim3(16), dim3(256), 0, stream>>>(KF, vwT, v_b, fsum, Ksum, matT, vsum, tsc);
    k_out<float><<<dim3(144, 16), dim3(256), 0, stream>>>(featF, QnT, matT, vsum, tsc, gamma, out);
  }
}

// Round 5
// 453.176 us; speedup vs baseline: 1.0899x; 1.0899x over previous
//
#include <hip/hip_runtime.h>

// FeatureAggregationModule on MI355X.  Output f32.
//   feat = ReLU(A*x + bias)      A = conv_w * bn_scale*rsqrt(var+eps)  (bf16 MFMA)
//   Q = qw*feat, K = kw*feat     (bf16 MFMA, fused L2-norm -> QnT, Kn)
//   KF = Kn*feat^T, fsum = sum_n feat
//   matrix[m,c] = sum_cp vw[c,cp]*KF[m,cp] + vb[c]*Ksum[m]   (V eliminated)
//   value_sum[c] = vw[c,:]*fsum + N*vb[c]
//   tailor[n] = 1/(N + sum_m Qn[m,n]*(Ksum[m]+eps))
//   out = feat*(feat + gamma*tailor*(value_sum + matrix^T*Qn) + 1)
// R4->R5: LDS transpose-staging in k_conv/k_qk (kills strided scalar gathers),
// k_mat rewritten as MFMA. feat bf16 in ws (ws fits; f32-in-d_out fallback kept).

typedef short short8 __attribute__((ext_vector_type(8)));
typedef __bf16 bf16x8 __attribute__((ext_vector_type(8)));
typedef float f32x4 __attribute__((ext_vector_type(4)));

#define DEVFN static __device__ __forceinline__

static constexpr int NB = 16;
static constexpr int C = 256;
static constexpr int HW = 9216;
static constexpr float FN = 9216.0f;
static constexpr float EPS_ATT_C = 1e-6f;
static constexpr float EPS_BN_C = 1e-5f;
static constexpr int LSTR = 40;  // LDS row stride in u16 (80B = 5*16B, bank-spread)

DEVFN unsigned short f2b(float f) {
  unsigned u = __float_as_uint(f);
  u += 0x7FFFu + ((u >> 16) & 1u);
  return (unsigned short)(u >> 16);
}
DEVFN float b2f(unsigned short s) { return __uint_as_float(((unsigned)s) << 16); }

DEVFN float featval(float v) { return v; }
DEVFN float featval(unsigned short v) { return b2f(v); }
DEVFN void feat_store(float* p, float v) { *p = v; }
DEVFN void feat_store(unsigned short* p, float v) { *p = f2b(v); }

DEVFN f32x4 mfma16(short8 a, short8 b, f32x4 c) {
  return __builtin_amdgcn_mfma_f32_16x16x32_bf16(
      __builtin_bit_cast(bf16x8, a), __builtin_bit_cast(bf16x8, b), c, 0, 0, 0);
}

// ---------------------------------------------------------------- k_prep
__global__ __launch_bounds__(256) void k_prep(
    const float* __restrict__ conv_w, const float* __restrict__ bn_scale,
    const float* __restrict__ bn_bias, const float* __restrict__ bn_mean,
    const float* __restrict__ bn_var, const float* __restrict__ q_w,
    const float* __restrict__ k_w, const float* __restrict__ v_w,
    unsigned short* __restrict__ Abf, float* __restrict__ biasA,
    unsigned short* __restrict__ qwbf, unsigned short* __restrict__ kwbf,
    unsigned short* __restrict__ vwbf, float* __restrict__ fsum,
    float* __restrict__ Ksum, float* __restrict__ KF) {
  int tid = blockIdx.x * 256 + threadIdx.x;
  int nth = gridDim.x * 256;
  for (int i = tid; i < 65536; i += nth) {
    int o = i >> 8;
    float sc = bn_scale[o] * rsqrtf(bn_var[o] + EPS_BN_C);
    Abf[i] = f2b(conv_w[i] * sc);
  }
  for (int i = tid; i < 256; i += nth) {
    float sc = bn_scale[i] * rsqrtf(bn_var[i] + EPS_BN_C);
    biasA[i] = bn_bias[i] - bn_mean[i] * sc;
  }
  for (int i = tid; i < 8192; i += nth) {
    qwbf[i] = f2b(q_w[i]);
    kwbf[i] = f2b(k_w[i]);
  }
  for (int i = tid; i < 65536; i += nth) vwbf[i] = f2b(v_w[i]);
  for (int i = tid; i < NB * 256; i += nth) fsum[i] = 0.f;
  for (int i = tid; i < NB * 32; i += nth) Ksum[i] = 0.f;
  for (int i = tid; i < NB * 32 * 256; i += nth) KF[i] = 0.f;
}

// ---------------------------------------------------------------- k_conv
// Tile 256o x 64p. Per k-step (32c): stage x slab into LDS transposed [p][c]
// (coalesced float4 global loads), fragments via ds_read_b128.
template <typename FT>
__global__ __launch_bounds__(256) void k_conv(
    const float* __restrict__ fsp, const float* __restrict__ fcp,
    const unsigned short* __restrict__ Abf, const float* __restrict__ biasA,
    FT* __restrict__ feat, float* __restrict__ fsum) {
  __shared__ unsigned short xl[2][64 * LSTR];
  const int b = blockIdx.y;
  const int p0 = blockIdx.x * 64;
  const int tid = threadIdx.x;
  const int w = tid >> 6, lane = tid & 63, g = lane >> 4, li = lane & 15;
  const int sc = tid & 31, spg = tid >> 5;  // staging: channel sc, px group spg*8

  f32x4 acc[4][4];
#pragma unroll
  for (int i = 0; i < 4; ++i)
#pragma unroll
    for (int j = 0; j < 4; ++j) acc[i][j] = f32x4{0.f, 0.f, 0.f, 0.f};

  const short* Ab = (const short*)Abf;

#pragma unroll 1
  for (int kk = 0; kk < 256; kk += 32) {
    const int ks = (kk >> 5) & 1;
    const float* src = (kk < 128)
        ? (fsp + ((size_t)b * 128 + kk + sc) * HW)
        : (fcp + ((size_t)b * 128 + (kk - 128) + sc) * HW);
    f32x4 x0 = *(const f32x4*)(src + p0 + spg * 8);
    f32x4 x1 = *(const f32x4*)(src + p0 + spg * 8 + 4);
    unsigned short* dst = &xl[ks][(spg * 8) * LSTR + sc];
#pragma unroll
    for (int i = 0; i < 4; ++i) dst[i * LSTR] = f2b(x0[i]);
#pragma unroll
    for (int i = 0; i < 4; ++i) dst[(4 + i) * LSTR] = f2b(x1[i]);
    __syncthreads();

    short8 af[4];
#pragma unroll
    for (int i = 0; i < 4; ++i)
      af[i] = *(const short8*)(Ab + (w * 64 + i * 16 + li) * 256 + kk + g * 8);
    short8 bfr[4];
#pragma unroll
    for (int j = 0; j < 4; ++j)
      bfr[j] = *(const short8*)&xl[ks][(j * 16 + li) * LSTR + g * 8];
#pragma unroll
    for (int i = 0; i < 4; ++i)
#pragma unroll
      for (int j = 0; j < 4; ++j)
        acc[i][j] = mfma16(af[i], bfr[j], acc[i][j]);
  }

  FT* fb = feat + (size_t)b * C * HW;
#pragma unroll
  for (int i = 0; i < 4; ++i) {
#pragma unroll
    for (int r = 0; r < 4; ++r) {
      int o = w * 64 + i * 16 + g * 4 + r;
      float bias = biasA[o];
      float s = 0.f;
#pragma unroll
      for (int j = 0; j < 4; ++j) {
        int p = p0 + j * 16 + li;
        float v = fmaxf(acc[i][j][r] + bias, 0.f);
        feat_store(&fb[(size_t)o * HW + p], v);
        s += v;
      }
      s += __shfl_xor(s, 1); s += __shfl_xor(s, 2);
      s += __shfl_xor(s, 4); s += __shfl_xor(s, 8);
      if (li == 0) atomicAdd(&fsum[b * 256 + o], s);
    }
  }
}

// ---------------------------------------------------------------- k_qk
// Tile 256p per block. Per k-step: stage feat slab [32c x 256p] -> LDS [p][c].
template <typename FT>
__global__ __launch_bounds__(256) void k_qk(
    const FT* __restrict__ feat, const unsigned short* __restrict__ qwbf,
    const unsigned short* __restrict__ kwbf, const float* __restrict__ q_b,
    const float* __restrict__ k_b, unsigned short* __restrict__ QnT,
    unsigned short* __restrict__ Kn, float* __restrict__ Ksum) {
  __shared__ unsigned short fl[2][256 * LSTR];
  const int b = blockIdx.y;
  const int tid = threadIdx.x;
  const int w = tid >> 6, lane = tid & 63, g = lane >> 4, li = lane & 15;
  const int p0b = blockIdx.x * 256;
  const int p0 = p0b + w * 64;
  const int sc = tid & 31, spg = tid >> 5;  // staging: channel sc, px group spg*32

  const FT* fs = feat + (size_t)b * C * HW;
  const short* qw = (const short*)qwbf;
  const short* kw = (const short*)kwbf;

  f32x4 aq[4][2], ak[2][4];
#pragma unroll
  for (int t = 0; t < 4; ++t)
#pragma unroll
    for (int m = 0; m < 2; ++m) {
      aq[t][m] = f32x4{0.f, 0.f, 0.f, 0.f};
      ak[m][t] = f32x4{0.f, 0.f, 0.f, 0.f};
    }

#pragma unroll 1
  for (int kk = 0; kk < 256; kk += 32) {
    const int ks = (kk >> 5) & 1;
    const FT* srow = fs + (size_t)(kk + sc) * HW + p0b + spg * 32;
    unsigned short* dst = &fl[ks][(spg * 32) * LSTR + sc];
    if constexpr (__is_same(FT, unsigned short)) {
#pragma unroll
      for (int q = 0; q < 4; ++q) {
        short8 v = *(const short8*)((const short*)srow + q * 8);
#pragma unroll
        for (int i = 0; i < 8; ++i) dst[(q * 8 + i) * LSTR] = (unsigned short)v[i];
      }
    } else {
#pragma unroll
      for (int q = 0; q < 8; ++q) {
        f32x4 v = *(const f32x4*)((const float*)srow + q * 4);
#pragma unroll
        for (int i = 0; i < 4; ++i) dst[(q * 4 + i) * LSTR] = f2b(v[i]);
      }
    }
    __syncthreads();

    short8 ft[4];
#pragma unroll
    for (int t = 0; t < 4; ++t)
      ft[t] = *(const short8*)&fl[ks][(w * 64 + t * 16 + li) * LSTR + g * 8];
    short8 qf[2], kf[2];
#pragma unroll
    for (int m = 0; m < 2; ++m) {
      qf[m] = *(const short8*)(qw + (m * 16 + li) * 256 + kk + g * 8);
      kf[m] = *(const short8*)(kw + (m * 16 + li) * 256 + kk + g * 8);
    }
#pragma unroll
    for (int t = 0; t < 4; ++t)
#pragma unroll
      for (int m = 0; m < 2; ++m)
        aq[t][m] = mfma16(ft[t], qf[m], aq[t][m]);
#pragma unroll
    for (int m = 0; m < 2; ++m)
#pragma unroll
      for (int t = 0; t < 4; ++t)
        ak[m][t] = mfma16(kf[m], ft[t], ak[m][t]);
  }

  // Q epilogue: row p = p0+16t+4g+r, col m = 16*jm+li
  float qb0 = q_b[li], qb1 = q_b[16 + li];
#pragma unroll
  for (int t = 0; t < 4; ++t) {
#pragma unroll
    for (int r = 0; r < 4; ++r) {
      float v0 = aq[t][0][r] + qb0;
      float v1 = aq[t][1][r] + qb1;
      float ss = v0 * v0 + v1 * v1;
      ss += __shfl_xor(ss, 1); ss += __shfl_xor(ss, 2);
      ss += __shfl_xor(ss, 4); ss += __shfl_xor(ss, 8);
      float sc2 = 1.0f / sqrtf(ss);
      int p = p0 + t * 16 + g * 4 + r;
      unsigned short* qp = QnT + ((size_t)b * HW + p) * 32;
      qp[li] = f2b(v0 * sc2);
      qp[16 + li] = f2b(v1 * sc2);
    }
  }

  // K epilogue: row m = 16*mi+4g+r, col p = p0+16t+li
  float kb[2][4];
#pragma unroll
  for (int mi = 0; mi < 2; ++mi)
#pragma unroll
    for (int r = 0; r < 4; ++r) kb[mi][r] = k_b[mi * 16 + g * 4 + r];

  float ksum_r[2][4];
#pragma unroll
  for (int mi = 0; mi < 2; ++mi)
#pragma unroll
    for (int r = 0; r < 4; ++r) ksum_r[mi][r] = 0.f;

#pragma unroll
  for (int t = 0; t < 4; ++t) {
    float v[2][4];
    float ss = 0.f;
#pragma unroll
    for (int mi = 0; mi < 2; ++mi)
#pragma unroll
      for (int r = 0; r < 4; ++r) {
        v[mi][r] = ak[mi][t][r] + kb[mi][r];
        ss += v[mi][r] * v[mi][r];
      }
    ss += __shfl_xor(ss, 16); ss += __shfl_xor(ss, 32);
    float sc2 = 1.0f / sqrtf(ss);
    int p = p0 + t * 16 + li;
#pragma unroll
    for (int mi = 0; mi < 2; ++mi)
#pragma unroll
      for (int r = 0; r < 4; ++r) {
        float kn = v[mi][r] * sc2;
        Kn[((size_t)b * 32 + mi * 16 + g * 4 + r) * HW + p] = f2b(kn);
        ksum_r[mi][r] += kn;
      }
  }
#pragma unroll
  for (int mi = 0; mi < 2; ++mi)
#pragma unroll
    for (int r = 0; r < 4; ++r) {
      float s = ksum_r[mi][r];
      s += __shfl_xor(s, 1); s += __shfl_xor(s, 2);
      s += __shfl_xor(s, 4); s += __shfl_xor(s, 8);
      if (li == 0) atomicAdd(&Ksum[b * 32 + mi * 16 + g * 4 + r], s);
    }
}

// ---------------------------------------------------------------- k_kf
template <typename FT>
__global__ __launch_bounds__(256) void k_kf(
    const unsigned short* __restrict__ Kn, const FT* __restrict__ feat,
    float* __restrict__ KF) {
  const int b = blockIdx.y;
  const int n0 = blockIdx.x * 256;
  const int tid = threadIdx.x;
  const int w = tid >> 6, lane = tid & 63, g = lane >> 4, li = lane & 15;
  const short* kn = (const short*)Kn + (size_t)b * 32 * HW;
  const FT* fs = feat + (size_t)b * C * HW;

  f32x4 acc[2][4];
#pragma unroll
  for (int mi = 0; mi < 2; ++mi)
#pragma unroll
    for (int j = 0; j < 4; ++j) acc[mi][j] = f32x4{0.f, 0.f, 0.f, 0.f};

#pragma unroll 1
  for (int s = 0; s < 8; ++s) {
    int nn = n0 + s * 32;
    short8 a[2], bb[4];
#pragma unroll
    for (int mi = 0; mi < 2; ++mi)
      a[mi] = *(const short8*)(kn + (size_t)(mi * 16 + li) * HW + nn + g * 8);
#pragma unroll
    for (int j = 0; j < 4; ++j) {
      const FT* fp = fs + (size_t)(w * 64 + j * 16 + li) * HW + nn + g * 8;
      if constexpr (__is_same(FT, unsigned short)) {
        bb[j] = *(const short8*)fp;
      } else {
        f32x4 x0 = *(const f32x4*)fp;
        f32x4 x1 = *(const f32x4*)(fp + 4);
#pragma unroll
        for (int jj = 0; jj < 4; ++jj) {
          bb[j][jj] = (short)f2b(x0[jj]);
          bb[j][4 + jj] = (short)f2b(x1[jj]);
        }
      }
    }
#pragma unroll
    for (int mi = 0; mi < 2; ++mi)
#pragma unroll
      for (int j = 0; j < 4; ++j)
        acc[mi][j] = mfma16(a[mi], bb[j], acc[mi][j]);
  }
  float* kfp = KF + (size_t)b * 32 * 256;
#pragma unroll
  for (int mi = 0; mi < 2; ++mi)
#pragma unroll
    for (int j = 0; j < 4; ++j)
#pragma unroll
      for (int r = 0; r < 4; ++r) {
        int m = mi * 16 + g * 4 + r;
        int c = w * 64 + j * 16 + li;
        atomicAdd(&kfp[m * 256 + c], acc[mi][j][r]);
      }
}

// ---------------------------------------------------------------- k_mat
// matrix[c][m] = sum_cp vw[c][cp]*KF[m][cp] via MFMA (A=vwbf, B=KF->bf16).
// vsum[c] = sum_cp vw[c][cp]*fsum[cp] + N*vb[c].  One block per batch.
__global__ __launch_bounds__(256) void k_mat(
    const float* __restrict__ KF, const unsigned short* __restrict__ vwbf,
    const float* __restrict__ v_b, const float* __restrict__ fsum,
    const float* __restrict__ Ksum, unsigned short* __restrict__ matT,
    float* __restrict__ vsum, float* __restrict__ tsc) {
  __shared__ float fs_l[256];
  const int b = blockIdx.x;
  const int tid = threadIdx.x;
  const int w = tid >> 6, lane = tid & 63, g = lane >> 4, li = lane & 15;
  fs_l[tid] = fsum[b * 256 + tid];
  if (tid < 32) tsc[b * 32 + tid] = Ksum[b * 32 + tid] + EPS_ATT_C;
  __syncthreads();

  const short* vw = (const short*)vwbf;
  const float* kfb = KF + (size_t)b * 8192;

  f32x4 acc[4][2];
#pragma unroll
  for (int i = 0; i < 4; ++i)
#pragma unroll
    for (int jm = 0; jm < 2; ++jm) acc[i][jm] = f32x4{0.f, 0.f, 0.f, 0.f};

#pragma unroll 1
  for (int kk = 0; kk < 256; kk += 32) {
    short8 af[4];
#pragma unroll
    for (int i = 0; i < 4; ++i)
      af[i] = *(const short8*)(vw + (w * 64 + i * 16 + li) * 256 + kk + g * 8);
    short8 bf[2];
#pragma unroll
    for (int jm = 0; jm < 2; ++jm) {
      const float* kp = kfb + (jm * 16 + li) * 256 + kk + g * 8;
      f32x4 x0 = *(const f32x4*)kp;
      f32x4 x1 = *(const f32x4*)(kp + 4);
#pragma unroll
      for (int jj = 0; jj < 4; ++jj) {
        bf[jm][jj] = (short)f2b(x0[jj]);
        bf[jm][4 + jj] = (short)f2b(x1[jj]);
      }
    }
#pragma unroll
    for (int i = 0; i < 4; ++i)
#pragma unroll
      for (int jm = 0; jm < 2; ++jm)
        acc[i][jm] = mfma16(af[i], bf[jm], acc[i][jm]);
  }

  // vsum (bf16 vw, fsum broadcast from LDS)
  {
    const int c = tid;
    float vs = 0.f;
    for (int cp = 0; cp < 256; ++cp)
      vs += b2f((unsigned short)vw[c * 256 + cp]) * fs_l[cp];
    vsum[b * 256 + c] = vs + FN * v_b[c];
  }

  // matT[c][m] = acc + vb[c]*Ksum[m]; D row c = w*64+i*16+g*4+r, col m = jm*16+li
  float ks0 = Ksum[b * 32 + li];
  float ks1 = Ksum[b * 32 + 16 + li];
#pragma unroll
  for (int i = 0; i < 4; ++i) {
#pragma unroll
    for (int r = 0; r < 4; ++r) {
      int cc = w * 64 + i * 16 + g * 4 + r;
      float vb = v_b[cc];
      unsigned short* mp = matT + ((size_t)b * 256 + cc) * 32;
      mp[li] = f2b(acc[i][0][r] + vb * ks0);
      mp[16 + li] = f2b(acc[i][1][r] + vb * ks1);
    }
  }
}

// ---------------------------------------------------------------- k_out
template <typename FT>
__global__ __launch_bounds__(256) void k_out(
    const FT* feat, const unsigned short* __restrict__ QnT,
    const unsigned short* __restrict__ matT, const float* __restrict__ vsum,
    const float* __restrict__ tsc, const float* __restrict__ gamma,
    float* out) {
  __shared__ float tail_l[64];
  __shared__ float vs_l[256];
  const int b = blockIdx.y;
  const int n0 = blockIdx.x * 64;
  const int tid = threadIdx.x;
  const int w = tid >> 6, lane = tid & 63, g = lane >> 4, li = lane & 15;
  const short* qn = (const short*)QnT + (size_t)b * HW * 32;

  vs_l[tid] = vsum[b * 256 + tid];
  if (tid < 64) {
    const short* qr = qn + (size_t)(n0 + tid) * 32;
    float d = 0.f;
#pragma unroll
    for (int m = 0; m < 32; ++m) d += b2f((unsigned short)qr[m]) * tsc[b * 32 + m];
    tail_l[tid] = 1.0f / (FN + d);
  }
  __syncthreads();

  const short* mt = (const short*)matT + (size_t)b * 256 * 32;
  short8 am[4], bq[4];
#pragma unroll
  for (int i = 0; i < 4; ++i)
    am[i] = *(const short8*)(mt + (w * 64 + i * 16 + li) * 32 + g * 8);
#pragma unroll
  for (int j = 0; j < 4; ++j)
    bq[j] = *(const short8*)(qn + (size_t)(n0 + j * 16 + li) * 32 + g * 8);

  f32x4 acc[4][4];
#pragma unroll
  for (int i = 0; i < 4; ++i)
#pragma unroll
    for (int j = 0; j < 4; ++j) {
      f32x4 z = f32x4{0.f, 0.f, 0.f, 0.f};
      acc[i][j] = mfma16(am[i], bq[j], z);
    }

  const float gam = gamma[0];
  const FT* fb = feat + (size_t)b * C * HW;
  float* ob = out + (size_t)b * C * HW;
#pragma unroll
  for (int i = 0; i < 4; ++i) {
#pragma unroll
    for (int r = 0; r < 4; ++r) {
      int c = w * 64 + i * 16 + g * 4 + r;
      float vsc = vs_l[c];
#pragma unroll
      for (int j = 0; j < 4; ++j) {
        int nl = j * 16 + li;
        float ms = acc[i][j][r] + vsc;
        float wv = tail_l[nl] * ms;
        float f = featval(fb[(size_t)c * HW + n0 + nl]);
        ob[(size_t)c * HW + n0 + nl] = f * (f + gam * wv + 1.0f);
      }
    }
  }
}

// ---------------------------------------------------------------- launch
extern "C" void kernel_launch(void* const* d_in, const int* in_sizes, int n_in,
                              void* d_out, int out_size, void* d_ws, size_t ws_size,
                              hipStream_t stream) {
  const float* fsp = (const float*)d_in[0];
  const float* fcp = (const float*)d_in[1];
  const float* conv_w = (const float*)d_in[2];
  const float* bn_scale = (const float*)d_in[3];
  const float* bn_bias = (const float*)d_in[4];
  const float* bn_mean = (const float*)d_in[5];
  const float* bn_var = (const float*)d_in[6];
  const float* gamma = (const float*)d_in[7];
  const float* q_w = (const float*)d_in[8];
  const float* q_b = (const float*)d_in[9];
  const float* k_w = (const float*)d_in[10];
  const float* k_b = (const float*)d_in[11];
  const float* v_w = (const float*)d_in[12];
  const float* v_b = (const float*)d_in[13];

  char* ws = (char*)d_ws;
  size_t off = 0;
  auto alloc = [&](size_t bytes) {
    off = (off + 255) & ~(size_t)255;
    void* p = ws + off;
    off += bytes;
    return p;
  };
  const size_t featBytesBf16 = (size_t)NB * C * HW * 2;
  unsigned short* featB = (unsigned short*)alloc(featBytesBf16);
  unsigned short* QnT  = (unsigned short*)alloc((size_t)NB * HW * 32 * 2);
  unsigned short* Kn   = (unsigned short*)alloc((size_t)NB * 32 * HW * 2);
  unsigned short* Abf  = (unsigned short*)alloc(65536 * 2);
  float* biasA = (float*)alloc(256 * 4);
  unsigned short* qwbf = (unsigned short*)alloc(8192 * 2);
  unsigned short* kwbf = (unsigned short*)alloc(8192 * 2);
  unsigned short* vwbf = (unsigned short*)alloc(65536 * 2);
  float* fsum = (float*)alloc(NB * 256 * 4);
  float* Ksum = (float*)alloc(NB * 32 * 4);
  float* tsc  = (float*)alloc(NB * 32 * 4);
  float* KF   = (float*)alloc((size_t)NB * 32 * 256 * 4);
  unsigned short* matT = (unsigned short*)alloc((size_t)NB * 256 * 32 * 2);
  float* vsum = (float*)alloc(NB * 256 * 4);
  const bool bf16path = (off <= ws_size);
  if (!bf16path) {
    off = 0;
    QnT  = (unsigned short*)alloc((size_t)NB * HW * 32 * 2);
    Kn   = (unsigned short*)alloc((size_t)NB * 32 * HW * 2);
    Abf  = (unsigned short*)alloc(65536 * 2);
    biasA = (float*)alloc(256 * 4);
    qwbf = (unsigned short*)alloc(8192 * 2);
    kwbf = (unsigned short*)alloc(8192 * 2);
    vwbf = (unsigned short*)alloc(65536 * 2);
    fsum = (float*)alloc(NB * 256 * 4);
    Ksum = (float*)alloc(NB * 32 * 4);
    tsc  = (float*)alloc(NB * 32 * 4);
    KF   = (float*)alloc((size_t)NB * 32 * 256 * 4);
    matT = (unsigned short*)alloc((size_t)NB * 256 * 32 * 2);
    vsum = (float*)alloc(NB * 256 * 4);
  }
  float* featF = (float*)d_out;
  float* out = (float*)d_out;

  k_prep<<<dim3(64), dim3(256), 0, stream>>>(conv_w, bn_scale, bn_bias, bn_mean,
                                             bn_var, q_w, k_w, v_w, Abf, biasA,
                                             qwbf, kwbf, vwbf, fsum, Ksum, KF);
  if (bf16path) {
    k_conv<unsigned short><<<dim3(144, 16), dim3(256), 0, stream>>>(fsp, fcp, Abf, biasA, featB, fsum);
    k_qk<unsigned short><<<dim3(36, 16), dim3(256), 0, stream>>>(featB, qwbf, kwbf, q_b, k_b, QnT, Kn, Ksum);
    k_kf<unsigned short><<<dim3(36, 16), dim3(256), 0, stream>>>(Kn, featB, KF);
    k_mat<<<dim3(16), dim3(256), 0, stream>>>(KF, vwbf, v_b, fsum, Ksum, matT, vsum, tsc);
    k_out<unsigned short><<<dim3(144, 16), dim3(256), 0, stream>>>(featB, QnT, matT, vsum, tsc, gamma, out);
  } else {
    k_conv<float><<<dim3(144, 16), dim3(256), 0, stream>>>(fsp, fcp, Abf, biasA, featF, fsum);
    k_qk<float><<<dim3(36, 16), dim3(256), 0, stream>>>(featF, qwbf, kwbf, q_b, k_b, QnT, Kn, Ksum);
    k_kf<float><<<dim3(36, 16), dim3(256), 0, stream>>>(Kn, featF, KF);
    k_mat<<<dim3(16), dim3(256), 0, stream>>>(KF, vwbf, v_b, fsum, Ksum, matT, vsum, tsc);
    k_out<float><<<dim3(144, 16), dim3(256), 0, stream>>>(featF, QnT, matT, vsum, tsc, gamma, out);
  }
}